// Round 1
// baseline (226.936 us; speedup 1.0000x reference)
//
#include <hip/hip_runtime.h>
#include <cstdint>
#include <cstddef>

// Problem constants
#define NB   32    // query batch
#define NSUP 25    // support images
#define KCLS 5     // classes
#define NC   512   // input channels
#define ND   128   // dk = dv
#define NP   196   // h*w
#define JS   208   // per-support padded spatial (13*16)
#define SHIFT 8.0f // fixed logit shift (softmax-invariant overflow guard)

typedef __attribute__((ext_vector_type(8))) short short8;   // 8 x bf16 (4 VGPRs)
typedef __attribute__((ext_vector_type(4))) float floatx4;  // MFMA C/D

__device__ inline short f2bf(float x) {
  union { float f; uint32_t u; } v; v.f = x;
  uint32_t r = (v.u + 0x7FFFu + ((v.u >> 16) & 1u)) >> 16;  // RNE
  return (short)(r & 0xFFFFu);
}
__device__ inline uint32_t pk2(float a, float b) {
  return (uint32_t)(uint16_t)f2bf(a) | ((uint32_t)(uint16_t)f2bf(b) << 16);
}

// ---------------------------------------------------------------------------
// Kernel 0: W fp32 -> bf16. Whi[mat][d:128][c:512], mats contiguous.
// ---------------------------------------------------------------------------
__global__ __launch_bounds__(256) void wconv_kernel(
    const float* __restrict__ Wqk, const float* __restrict__ Wv,
    uint16_t* __restrict__ Whi)
{
  const int f = (blockIdx.x * 256 + (int)threadIdx.x) * 8;   // < 131072
  const float* src = (f < ND * NC) ? (Wqk + f) : (Wv + f - ND * NC);
  short8 hv;
  #pragma unroll
  for (int i = 0; i < 8; ++i) hv[i] = f2bf(src[i]);
  *(short8*)(Whi + f) = hv;
}

// ---------------------------------------------------------------------------
// Kernel 1: fused projection GEMM (unchanged, verified).
//   QK: A=X(m=p), B=Wqk(n=d) -> bf16 Qt[b][p<196][d] / Kt[n][p:208][d]
//   V:  A=Wv(m=d), B=X(n=p)  -> bf16 Vt[n][d][p:208] / fp32 outVq[b][d][p]
// ---------------------------------------------------------------------------
__global__ __launch_bounds__(256) void gemm_kernel(
    const float* __restrict__ supp, const float* __restrict__ qry,
    const uint16_t* __restrict__ Whi,
    uint16_t* __restrict__ Qt, uint16_t* __restrict__ Kt,
    uint16_t* __restrict__ Vt, float* __restrict__ outVq)
{
  __shared__ uint16_t xs[16 * 520];     // 16.6 KB bf16 X tile, [p][c+pad]
  const int bx = blockIdx.x;
  const int t16 = bx % 13, img = bx / 13;
  const int tid = (int)threadIdx.x;
  const int w = tid >> 6, lane = tid & 63, ln = lane & 15, q = lane >> 4;
  const int d0 = w * 32;
  const int p0 = t16 * 16;

  const float* __restrict__ X = (img < NB)
      ? (qry  + (size_t)img * NC * NP)
      : (supp + (size_t)(img - NB) * NC * NP);

  // stage X tile as bf16: read float4 along p, write packed pairs along c
  #pragma unroll
  for (int k = 0; k < 4; ++k) {
    const int id = k * 256 + tid;
    const int cp = id >> 2;                        // c-pair: c = 2cp, 2cp+1
    const int pq = id & 3;
    int pg = p0 + pq * 4; if (pg > NP - 4) pg = NP - 4;   // clamp (pad rows masked later)
    const floatx4 fa = *(const floatx4*)(X + (2 * cp) * NP + pg);
    const floatx4 fb = *(const floatx4*)(X + (2 * cp + 1) * NP + pg);
    #pragma unroll
    for (int i = 0; i < 4; ++i)
      *((uint32_t*)xs + (pq * 4 + i) * 260 + cp) = pk2(fa[i], fb[i]);
  }
  __syncthreads();

  floatx4 aQ[2], aV[2];
  #pragma unroll
  for (int nt = 0; nt < 2; ++nt) {
    aQ[nt] = (floatx4){0.f, 0.f, 0.f, 0.f};
    aV[nt] = (floatx4){0.f, 0.f, 0.f, 0.f};
  }

  for (int ks = 0; ks < 16; ++ks) {
    const short8 xh = *(const short8*)&xs[ln * 520 + ks * 32 + q * 8];  // 1 ds_read_b128
    #pragma unroll
    for (int nt = 0; nt < 2; ++nt) {
      const size_t wr = (size_t)(d0 + nt * 16 + ln) * NC + ks * 32 + q * 8;
      const short8 wqh = *(const short8*)(Whi + wr);
      aQ[nt] = __builtin_amdgcn_mfma_f32_16x16x32_bf16(xh, wqh, aQ[nt], 0, 0, 0);
      const short8 wvh = *(const short8*)(Whi + (size_t)ND * NC + wr);
      aV[nt] = __builtin_amdgcn_mfma_f32_16x16x32_bf16(wvh, xh, aV[nt], 0, 0, 0);
    }
  }

  // QK: D row = p = p0+q*4+rr, col = d = d0+nt*16+ln
  if (img < NB) {
    #pragma unroll
    for (int nt = 0; nt < 2; ++nt)
      #pragma unroll
      for (int rr = 0; rr < 4; ++rr) {
        const int p = p0 + q * 4 + rr;
        if (p < NP)
          Qt[((size_t)img * NP + p) * ND + d0 + nt * 16 + ln] = (uint16_t)f2bf(aQ[nt][rr]);
      }
  } else {
    const int n = img - NB;
    #pragma unroll
    for (int nt = 0; nt < 2; ++nt)
      #pragma unroll
      for (int rr = 0; rr < 4; ++rr) {
        const int p = p0 + q * 4 + rr;              // 0..207, pads masked in attn
        Kt[((size_t)n * JS + p) * ND + d0 + nt * 16 + ln] = (uint16_t)f2bf(aQ[nt][rr]);
      }
  }
  // V: D row = d = d0+nt*16+q*4+rr, col = p = p0+ln
  const int p = p0 + ln;
  if (img < NB) {
    if (p < NP) {
      #pragma unroll
      for (int nt = 0; nt < 2; ++nt)
        #pragma unroll
        for (int rr = 0; rr < 4; ++rr)
          outVq[((size_t)img * ND + d0 + nt * 16 + q * 4 + rr) * NP + p] = aV[nt][rr];
    }
  } else {
    const int n = img - NB;
    #pragma unroll
    for (int nt = 0; nt < 2; ++nt)
      #pragma unroll
      for (int rr = 0; rr < 4; ++rr)
        Vt[((size_t)n * ND + d0 + nt * 16 + q * 4 + rr) * JS + p] = (uint16_t)f2bf(aV[nt][rr]);
  }
}

// ---------------------------------------------------------------------------
// Kernel 2: per-class masked attention, NO LDS STAGING.
// Kt+Vt total 2.66 MB -> L2-resident; each lane reads its MFMA fragments
// directly from global as one 16B load each (identical bytes the old staging
// moved through LDS). Register double-buffer (bkA/avA vs bkB/avB, static
// names -> no scratch) prefetches chunk i+1's 16 frag loads while chunk i
// computes; no __syncthreads anywhere in the loop. The 4 waves of a block
// read the SAME K/V addresses (they differ only in b) -> L1 dedup keeps L2
// traffic at the staged level (~280 MB). QK/exp/bpermute/PV math verbatim
// from the verified version -> bit-identical output.
// grid = 8*5*13 = 520 x 256.
// ---------------------------------------------------------------------------

// Load chunk CH's K/V fragments straight from global.
// K frag (A, m=j): lane(ln,q) -> Kt[(n*JS + j0 + ln)*ND + ks*32 + q*8]
// V frag (A, m=d): lane(ln,q) -> Vt[(n*ND + dt*16 + ln)*JS + jv[h] + (q&1)*8], h=q>>1
#define LOAD_FRAGS(BK, AV, CH) do {                                            \
    _Pragma("unroll")                                                          \
    for (int t_ = 0; t_ < 2; ++t_) {                                           \
      const int tile16_ = (CH) * 2 + t_;                                       \
      int s_ = tile16_ / 13;                                                   \
      const int j0_ = (tile16_ - s_ * 13) * 16;                                \
      if (s_ > 4) s_ = 4;                                                      \
      const int n_ = (clsPack >> (6 * s_)) & 63;                               \
      const uint16_t* kr_ = Kt + ((size_t)(n_ * JS + j0_ + ln)) * ND + q * 8;  \
      _Pragma("unroll")                                                        \
      for (int ks_ = 0; ks_ < 4; ++ks_)                                        \
        BK[t_][ks_] = *(const short8*)(kr_ + ks_ * 32);                        \
    }                                                                          \
    {                                                                          \
      const int h_ = q >> 1;                                                   \
      const int ch_ = (CH) * 32 + h_ * 16;                                     \
      int sv_ = ch_ / JS, jv_ = ch_ - sv_ * JS;                                \
      if (sv_ > 4) { sv_ = 4; jv_ = 192; }                                     \
      const int n_ = (clsPack >> (6 * sv_)) & 63;                              \
      const uint16_t* vr_ = Vt + ((size_t)n_ * ND + ln) * JS + jv_ + (q & 1) * 8; \
      _Pragma("unroll")                                                        \
      for (int dt_ = 0; dt_ < 8; ++dt_)                                        \
        AV[dt_] = *(const short8*)(vr_ + (size_t)(dt_ * 16) * JS);             \
    }                                                                          \
  } while (0)

// QK as S^T (A=K m=j, B=Q n=p), exp with pad masking, packed bpermute
// D-layout -> B-operand transform, PV accumulate. Verbatim math.
#define COMPUTE_CHUNK(BK, AV, CH) do {                                         \
    floatx4 e0_, e1_;                                                          \
    _Pragma("unroll")                                                          \
    for (int t_ = 0; t_ < 2; ++t_) {                                           \
      const int tile16_ = (CH) * 2 + t_;                                       \
      const int s_ = tile16_ / 13;                                             \
      const int j0_ = (tile16_ - s_ * 13) * 16;                                \
      const bool tval_ = (s_ < 5);                                             \
      floatx4 d4_ = {0.f, 0.f, 0.f, 0.f};                                      \
      _Pragma("unroll")                                                        \
      for (int ks_ = 0; ks_ < 4; ++ks_)                                        \
        d4_ = __builtin_amdgcn_mfma_f32_16x16x32_bf16(BK[t_][ks_], aq[ks_], d4_, 0, 0, 0); \
      floatx4 ev_;                                                             \
      _Pragma("unroll")                                                        \
      for (int r_ = 0; r_ < 4; ++r_) {                                         \
        const int j_ = j0_ + q * 4 + r_;                                       \
        const float e_ = (tval_ && j_ < NP) ? __expf(d4_[r_] - SHIFT) : 0.f;   \
        ev_[r_] = e_;                                                          \
        Ssum += e_;                                                            \
      }                                                                        \
      if (t_ == 0) e0_ = ev_; else e1_ = ev_;                                  \
    }                                                                          \
    short8 bp_;                                                                \
    _Pragma("unroll")                                                          \
    for (int r_ = 0; r_ < 4; ++r_) {                                           \
      const uint32_t pe_ = pk2(e0_[r_], e1_[r_]);                              \
      const int lo_ = __builtin_amdgcn_ds_bpermute(alo, (int)pe_);             \
      const int hi_ = __builtin_amdgcn_ds_bpermute(alo + 64, (int)pe_);        \
      bp_[r_]     = (short)(uint16_t)(hiTile ? (lo_ >> 16) : (lo_ & 0xFFFF));  \
      bp_[4 + r_] = (short)(uint16_t)(hiTile ? (hi_ >> 16) : (hi_ & 0xFFFF));  \
    }                                                                          \
    _Pragma("unroll")                                                          \
    for (int dt_ = 0; dt_ < 8; ++dt_)                                          \
      acc[dt_] = __builtin_amdgcn_mfma_f32_16x16x32_bf16(AV[dt_], bp_, acc[dt_], 0, 0, 0); \
  } while (0)

__global__ __launch_bounds__(256, 2) void attn_kernel(
    const uint16_t* __restrict__ Qt, const uint16_t* __restrict__ Kt,
    const uint16_t* __restrict__ Vt, const int* __restrict__ labels,
    float* __restrict__ out)
{
  const int bx = blockIdx.x;              // 520 = 8*5*13
  const int pt = bx % 13;
  const int rem = bx / 13;                // 40 = 8*5
  const int kc = rem % KCLS;
  const int b0 = (rem / KCLS) * 4;        // batch quad base
  const int p0 = pt * 16;
  const int tid = (int)threadIdx.x;
  const int w = tid >> 6, lane = tid & 63, ln = lane & 15, q = lane >> 4;
  const int b = b0 + w;                   // this wave's batch

  // class-support list packed in a register (6 bits/slot) via ballot
  const int myl = (lane < NSUP) ? labels[lane] : -1;
  unsigned long long m = __ballot(myl == kc);
  int clsPack = 0;
  #pragma unroll
  for (int s = 0; s < 5; ++s) {
    const int n = (m != 0ull) ? (int)__builtin_ctzll(m) : 0;
    clsPack |= n << (6 * s);
    m &= (m - 1);
  }

  // Q B-frags (resident): B[n=p][k=d]
  short8 aq[4];
  {
    int p = p0 + ln; if (p > NP - 1) p = NP - 1;
    const uint16_t* base = Qt + ((size_t)b * NP + p) * ND + q * 8;
    #pragma unroll
    for (int ks = 0; ks < 4; ++ks) aq[ks] = *(const short8*)(base + ks * 32);
  }

  floatx4 acc[8];
  #pragma unroll
  for (int dt = 0; dt < 8; ++dt) acc[dt] = (floatx4){0.f, 0.f, 0.f, 0.f};
  float Ssum = 0.f;

  const int alo = (ln + ((q & 1) << 5)) << 2;  // bpermute byte addr (verified)
  const bool hiTile = (q >= 2);

  // register double-buffered chunk pipeline: 33 chunks, 2 per iteration
  short8 bkA[2][4], avA[8], bkB[2][4], avB[8];
  LOAD_FRAGS(bkA, avA, 0);
  for (int it = 0; it < 32; it += 2) {
    LOAD_FRAGS(bkB, avB, it + 1);     // issue next chunk's 16 loads
    COMPUTE_CHUNK(bkA, avA, it);      // compute current while they fly
    LOAD_FRAGS(bkA, avA, it + 2);     // it+2 <= 32, always valid
    COMPUTE_CHUNK(bkB, avB, it + 1);
  }
  COMPUTE_CHUNK(bkA, avA, 32);        // tail chunk

  // ---- normalize and store (per wave; no merge needed) ----
  float sv = Ssum;
  sv += __shfl_xor(sv, 16);
  sv += __shfl_xor(sv, 32);
  const float inv = 1.f / sv;
  const int pp = p0 + ln;
  if (pp < NP) {
    float* ob = out + ((size_t)(b * KCLS + kc) * ND + q * 4) * NP + pp;
    #pragma unroll
    for (int dt = 0; dt < 8; ++dt)
      #pragma unroll
      for (int rr = 0; rr < 4; ++rr)
        ob[(size_t)(dt * 16 + rr) * NP] = acc[dt][rr] * inv;
  }
}

// ---------------------------------------------------------------------------
extern "C" void kernel_launch(void* const* d_in, const int* in_sizes, int n_in,
                              void* d_out, int out_size, void* d_ws, size_t ws_size,
                              hipStream_t stream) {
  const float* supp   = (const float*)d_in[0];
  const float* qry    = (const float*)d_in[1];
  const int*   labels = (const int*)d_in[2];
  const float* Wqk    = (const float*)d_in[3];
  const float* Wv     = (const float*)d_in[4];
  float* out = (float*)d_out;

  // ws layout (~4.6 MB)
  uint16_t* Whi = (uint16_t*)d_ws;                  // [2][128][512]
  uint16_t* Qt  = Whi + (size_t)2 * ND * NC;        // [32][196][128]
  uint16_t* Kt  = Qt  + (size_t)NB * NP * ND;       // [25][208][128]
  uint16_t* Vt  = Kt  + (size_t)NSUP * JS * ND;     // [25][128][208]
  float* outVq = out + (size_t)NB * KCLS * ND * NP; // query_v_flat region

  wconv_kernel<<<64, 256, 0, stream>>>(Wqk, Wv, Whi);
  gemm_kernel<<<741, 256, 0, stream>>>(supp, qry, Whi, Qt, Kt, Vt, outVq);
  attn_kernel<<<520, 256, 0, stream>>>(Qt, Kt, Vt, labels, out);
}

// Round 3
// 169.412 us; speedup vs baseline: 1.3396x; 1.3396x over previous
//
#include <hip/hip_runtime.h>
#include <cstdint>
#include <cstddef>

// Problem constants
#define NB   32    // query batch
#define NSUP 25    // support images
#define KCLS 5     // classes
#define NC   512   // input channels
#define ND   128   // dk = dv
#define NP   196   // h*w
#define JS   208   // per-support padded spatial (13*16)
#define SHIFT 8.0f // fixed logit shift (softmax-invariant overflow guard)

// attn LDS geometry (XOR-swizzled, no pads):
//   K: 4 tiles/iter x 16 rows x 256B  = 16384 B
//   V: 128 rows(d) x 128B (64 j)      = 16384 B
//   BUFSZ = 32768 B, double buffer = 65536 B total (single-bit ^0x8000 toggle)
#define KTILE  4096
#define VBASE  16384
#define BUFSZ  32768

typedef __attribute__((ext_vector_type(8))) short short8;   // 8 x bf16 (4 VGPRs)
typedef __attribute__((ext_vector_type(4))) float floatx4;  // MFMA C/D

__device__ inline short f2bf(float x) {
  union { float f; uint32_t u; } v; v.f = x;
  uint32_t r = (v.u + 0x7FFFu + ((v.u >> 16) & 1u)) >> 16;  // RNE
  return (short)(r & 0xFFFFu);
}
__device__ inline uint32_t pk2(float a, float b) {
  return (uint32_t)(uint16_t)f2bf(a) | ((uint32_t)(uint16_t)f2bf(b) << 16);
}

// ---------------------------------------------------------------------------
// Kernel 0: W fp32 -> bf16. Whi[mat][d:128][c:512], mats contiguous.
// ---------------------------------------------------------------------------
__global__ __launch_bounds__(256) void wconv_kernel(
    const float* __restrict__ Wqk, const float* __restrict__ Wv,
    uint16_t* __restrict__ Whi)
{
  const int f = (blockIdx.x * 256 + (int)threadIdx.x) * 8;   // < 131072
  const float* src = (f < ND * NC) ? (Wqk + f) : (Wv + f - ND * NC);
  short8 hv;
  #pragma unroll
  for (int i = 0; i < 8; ++i) hv[i] = f2bf(src[i]);
  *(short8*)(Whi + f) = hv;
}

// ---------------------------------------------------------------------------
// Kernel 1: fused projection GEMM (unchanged, verified).
//   QK: A=X(m=p), B=Wqk(n=d) -> bf16 Qt[b][p<196][d] / Kt[n][p:208][d]
//   V:  A=Wv(m=d), B=X(n=p)  -> bf16 Vt[n][d][p:208] / fp32 outVq[b][d][p]
// ---------------------------------------------------------------------------
__global__ __launch_bounds__(256) void gemm_kernel(
    const float* __restrict__ supp, const float* __restrict__ qry,
    const uint16_t* __restrict__ Whi,
    uint16_t* __restrict__ Qt, uint16_t* __restrict__ Kt,
    uint16_t* __restrict__ Vt, float* __restrict__ outVq)
{
  __shared__ uint16_t xs[16 * 520];     // 16.6 KB bf16 X tile, [p][c+pad]
  const int bx = blockIdx.x;
  const int t16 = bx % 13, img = bx / 13;
  const int tid = (int)threadIdx.x;
  const int w = tid >> 6, lane = tid & 63, ln = lane & 15, q = lane >> 4;
  const int d0 = w * 32;
  const int p0 = t16 * 16;

  const float* __restrict__ X = (img < NB)
      ? (qry  + (size_t)img * NC * NP)
      : (supp + (size_t)(img - NB) * NC * NP);

  // stage X tile as bf16: read float4 along p, write packed pairs along c
  #pragma unroll
  for (int k = 0; k < 4; ++k) {
    const int id = k * 256 + tid;
    const int cp = id >> 2;                        // c-pair: c = 2cp, 2cp+1
    const int pq = id & 3;
    int pg = p0 + pq * 4; if (pg > NP - 4) pg = NP - 4;   // clamp (pad rows masked later)
    const floatx4 fa = *(const floatx4*)(X + (2 * cp) * NP + pg);
    const floatx4 fb = *(const floatx4*)(X + (2 * cp + 1) * NP + pg);
    #pragma unroll
    for (int i = 0; i < 4; ++i)
      *((uint32_t*)xs + (pq * 4 + i) * 260 + cp) = pk2(fa[i], fb[i]);
  }
  __syncthreads();

  floatx4 aQ[2], aV[2];
  #pragma unroll
  for (int nt = 0; nt < 2; ++nt) {
    aQ[nt] = (floatx4){0.f, 0.f, 0.f, 0.f};
    aV[nt] = (floatx4){0.f, 0.f, 0.f, 0.f};
  }

  for (int ks = 0; ks < 16; ++ks) {
    const short8 xh = *(const short8*)&xs[ln * 520 + ks * 32 + q * 8];  // 1 ds_read_b128
    #pragma unroll
    for (int nt = 0; nt < 2; ++nt) {
      const size_t wr = (size_t)(d0 + nt * 16 + ln) * NC + ks * 32 + q * 8;
      const short8 wqh = *(const short8*)(Whi + wr);
      aQ[nt] = __builtin_amdgcn_mfma_f32_16x16x32_bf16(xh, wqh, aQ[nt], 0, 0, 0);
      const short8 wvh = *(const short8*)(Whi + (size_t)ND * NC + wr);
      aV[nt] = __builtin_amdgcn_mfma_f32_16x16x32_bf16(wvh, xh, aV[nt], 0, 0, 0);
    }
  }

  // QK: D row = p = p0+q*4+rr, col = d = d0+nt*16+ln
  if (img < NB) {
    #pragma unroll
    for (int nt = 0; nt < 2; ++nt)
      #pragma unroll
      for (int rr = 0; rr < 4; ++rr) {
        const int p = p0 + q * 4 + rr;
        if (p < NP)
          Qt[((size_t)img * NP + p) * ND + d0 + nt * 16 + ln] = (uint16_t)f2bf(aQ[nt][rr]);
      }
  } else {
    const int n = img - NB;
    #pragma unroll
    for (int nt = 0; nt < 2; ++nt)
      #pragma unroll
      for (int rr = 0; rr < 4; ++rr) {
        const int p = p0 + q * 4 + rr;              // 0..207, pads masked in attn
        Kt[((size_t)n * JS + p) * ND + d0 + nt * 16 + ln] = (uint16_t)f2bf(aQ[nt][rr]);
      }
  }
  // V: D row = d = d0+nt*16+q*4+rr, col = p = p0+ln
  const int p = p0 + ln;
  if (img < NB) {
    if (p < NP) {
      #pragma unroll
      for (int nt = 0; nt < 2; ++nt)
        #pragma unroll
        for (int rr = 0; rr < 4; ++rr)
          outVq[((size_t)img * ND + d0 + nt * 16 + q * 4 + rr) * NP + p] = aV[nt][rr];
    }
  } else {
    const int n = img - NB;
    #pragma unroll
    for (int nt = 0; nt < 2; ++nt)
      #pragma unroll
      for (int rr = 0; rr < 4; ++rr)
        Vt[((size_t)n * ND + d0 + nt * 16 + q * 4 + rr) * JS + p] = (uint16_t)f2bf(aV[nt][rr]);
  }
}

// ---------------------------------------------------------------------------
// Kernel 2: per-class masked attention. LDS-staged, double-buffered,
// 2 chunks (64 j) per iteration -> 17 iterations, 1 barrier each.
// XOR-swizzled LDS (byte ^= (row&7)<<4 on both write and read) => every
// ds op is 2-way per 16-lane phase (free, m136). All per-thread address
// components hoisted; per-iteration variables are 4 wave-uniform (s,j,n)
// triples from incremental scalar counters (no divisions in the loop).
// QK/exp/bpermute/PV math verbatim -> bit-identical output.
// Chunks padded 33 -> 34 (tail tiles s=5 masked: e=0, reads in-bounds).
// grid = 8*5*13 = 520 x 256.
// ---------------------------------------------------------------------------

#define DECODE() do {                                                          \
    _Pragma("unroll")                                                          \
    for (int t_ = 0; t_ < 4; ++t_) {                                           \
      dS[t_] = s_ctr; dJ[t_] = j_ctr;                                          \
      const int sc_ = s_ctr > 4 ? 4 : s_ctr;                                   \
      dN[t_] = (clsPack >> (6 * sc_)) & 63;                                    \
      j_ctr += 16; if (j_ctr >= JS) { j_ctr -= JS; s_ctr += 1; }               \
    }                                                                          \
  } while (0)

#define ISSUE() do {                                                           \
    _Pragma("unroll")                                                          \
    for (int p_ = 0; p_ < 4; ++p_)                                             \
      pf[p_] = *(const int4*)(Kt + (size_t)(dN[p_] * JS + dJ[p_]) * ND + kinv);\
    _Pragma("unroll")                                                          \
    for (int p_ = 0; p_ < 4; ++p_)                                             \
      pf[4 + p_] = *(const int4*)(Vt + (size_t)dN[p_] * (ND * JS) + dJ[p_] + vinv); \
  } while (0)

#define STORE() do {                                                           \
    _Pragma("unroll")                                                          \
    for (int p_ = 0; p_ < 4; ++p_)                                             \
      *(int4*)(smem + kstA + p_ * KTILE) = pf[p_];                             \
    _Pragma("unroll")                                                          \
    for (int p_ = 0; p_ < 4; ++p_)                                             \
      *(int4*)(smem + vstA[p_]) = pf[4 + p_];                                  \
  } while (0)

__global__ __launch_bounds__(256, 2) void attn_kernel(
    const uint16_t* __restrict__ Qt, const uint16_t* __restrict__ Kt,
    const uint16_t* __restrict__ Vt, const int* __restrict__ labels,
    float* __restrict__ out)
{
  __shared__ __align__(16) char smem[2 * BUFSZ];   // 64 KiB double buffer

  const int bx = blockIdx.x;              // 520 = 8*5*13
  const int pt = bx % 13;
  const int rem = bx / 13;                // 40 = 8*5
  const int kc = rem % KCLS;
  const int b0 = (rem / KCLS) * 4;        // batch quad base
  const int p0 = pt * 16;
  const int tid = (int)threadIdx.x;
  const int w = tid >> 6, lane = tid & 63, ln = lane & 15, q = lane >> 4;
  const int b = b0 + w;                   // this wave's batch

  // class-support list packed in a register (6 bits/slot) via ballot
  const int myl = (lane < NSUP) ? labels[lane] : -1;
  unsigned long long m = __ballot(myl == kc);
  int clsPack = 0;
  #pragma unroll
  for (int s = 0; s < 5; ++s) {
    const int n = (m != 0ull) ? (int)__builtin_ctzll(m) : 0;
    clsPack |= n << (6 * s);
    m &= (m - 1);
  }
  clsPack = __builtin_amdgcn_readfirstlane(clsPack);   // force SALU decode

  // Q B-frags (resident): B[n=p][k=d]
  short8 aq[4];
  {
    int p = p0 + ln; if (p > NP - 1) p = NP - 1;
    const uint16_t* base = Qt + ((size_t)b * NP + p) * ND + q * 8;
    #pragma unroll
    for (int ks = 0; ks < 4; ++ks) aq[ks] = *(const short8*)(base + ks * 32);
  }

  floatx4 acc[8];
  #pragma unroll
  for (int dt = 0; dt < 8; ++dt) acc[dt] = (floatx4){0.f, 0.f, 0.f, 0.f};
  float Ssum = 0.f;

  const int alo = (ln + ((q & 1) << 5)) << 2;  // bpermute byte addr (verified)
  const bool hiTile = (q >= 2);

  // ---- hoisted per-thread staging addresses (buf0 phase) ----
  const int rK = tid >> 4, scK = tid & 15;
  const int kinv = rK * ND + scK * 8;                        // K src, u16 units
  int kstA = rK * 256 + ((scK * 16) ^ ((rK & 7) << 4));      // K LDS store
  const int dV = tid >> 1, s2V = tid & 1;
  const int vinv = dV * JS + s2V * 8;                        // V src, u16 units
  int vstA[4];
  #pragma unroll
  for (int sub = 0; sub < 4; ++sub)
    vstA[sub] = VBASE + dV * 128 + ((((sub << 1) + s2V) ^ (dV & 7)) << 4);

  // frag read addresses (buf0 phase); tile/dt deltas are immediate offsets
  int kfrx[4], vfrx[2];
  #pragma unroll
  for (int ks = 0; ks < 4; ++ks)
    kfrx[ks] = ln * 256 + (((ks << 6) | (q << 4)) ^ ((ln & 7) << 4));
  #pragma unroll
  for (int c = 0; c < 2; ++c)
    vfrx[c] = VBASE + ln * 128 + ((((c << 2) | q) << 4) ^ ((ln & 7) << 4));

  // ---- prologue: decode/stage iteration 0 into buf0 ----
  int s_ctr = 0, j_ctr = 0;
  int dS[4], dJ[4], dN[4], cS[4], cJ[4];
  int4 pf[8];

  DECODE();
  ISSUE();
  STORE();                                 // kstA/vstA are buf0 phase
  kstA ^= BUFSZ;                           // stores now target buf1
  #pragma unroll
  for (int i = 0; i < 4; ++i) vstA[i] ^= BUFSZ;
  #pragma unroll
  for (int i = 0; i < 4; ++i) { cS[i] = dS[i]; cJ[i] = dJ[i]; }
  __syncthreads();

  for (int it = 0; it < 17; ++it) {
    if (it < 16) { DECODE(); ISSUE(); }    // next iteration's loads in flight

    // ---- compute 2 chunks from buffer (it&1) ----
    #pragma unroll
    for (int c = 0; c < 2; ++c) {
      short8 bk[2][4];
      #pragma unroll
      for (int t = 0; t < 2; ++t)
        #pragma unroll
        for (int ks = 0; ks < 4; ++ks)
          bk[t][ks] = *(const short8*)(smem + kfrx[ks] + (c * 2 + t) * KTILE);

      floatx4 e0, e1;
      #pragma unroll
      for (int t = 0; t < 2; ++t) {
        const int tt = c * 2 + t;
        floatx4 d4 = {0.f, 0.f, 0.f, 0.f};
        #pragma unroll
        for (int ks = 0; ks < 4; ++ks)
          d4 = __builtin_amdgcn_mfma_f32_16x16x32_bf16(bk[t][ks], aq[ks], d4, 0, 0, 0);
        floatx4 ev;
        #pragma unroll
        for (int r = 0; r < 4; ++r) {
          const int j = cJ[tt] + q * 4 + r;
          const float e = (cS[tt] < 5 && j < NP) ? __expf(d4[r] - SHIFT) : 0.f;
          ev[r] = e;
          Ssum += e;
        }
        if (t == 0) e0 = ev; else e1 = ev;
      }

      short8 bp;
      #pragma unroll
      for (int r = 0; r < 4; ++r) {
        const uint32_t pe = pk2(e0[r], e1[r]);
        const int lo = __builtin_amdgcn_ds_bpermute(alo, (int)pe);
        const int hi = __builtin_amdgcn_ds_bpermute(alo + 64, (int)pe);
        bp[r]     = (short)(uint16_t)(hiTile ? (lo >> 16) : (lo & 0xFFFF));
        bp[4 + r] = (short)(uint16_t)(hiTile ? (hi >> 16) : (hi & 0xFFFF));
      }

      short8 av[8];
      #pragma unroll
      for (int dt = 0; dt < 8; ++dt)
        av[dt] = *(const short8*)(smem + vfrx[c] + dt * 2048);
      #pragma unroll
      for (int dt = 0; dt < 8; ++dt)
        acc[dt] = __builtin_amdgcn_mfma_f32_16x16x32_bf16(av[dt], bp, acc[dt], 0, 0, 0);
    }

    if (it < 16) {
      STORE();                             // write next iteration's chunks
      #pragma unroll
      for (int i = 0; i < 4; ++i) { cS[i] = dS[i]; cJ[i] = dJ[i]; }
    }
    __syncthreads();

    // single-bit buffer toggle on all LDS address registers
    kstA ^= BUFSZ;
    #pragma unroll
    for (int i = 0; i < 4; ++i) vstA[i] ^= BUFSZ;
    #pragma unroll
    for (int i = 0; i < 4; ++i) kfrx[i] ^= BUFSZ;
    #pragma unroll
    for (int i = 0; i < 2; ++i) vfrx[i] ^= BUFSZ;
  }

  // ---- normalize and store (per wave; no merge needed) ----
  float sv = Ssum;
  sv += __shfl_xor(sv, 16);
  sv += __shfl_xor(sv, 32);
  const float inv = 1.f / sv;
  const int pp = p0 + ln;
  if (pp < NP) {
    float* ob = out + ((size_t)(b * KCLS + kc) * ND + q * 4) * NP + pp;
    #pragma unroll
    for (int dt = 0; dt < 8; ++dt)
      #pragma unroll
      for (int rr = 0; rr < 4; ++rr)
        ob[(size_t)(dt * 16 + rr) * NP] = acc[dt][rr] * inv;
  }
}

// ---------------------------------------------------------------------------
extern "C" void kernel_launch(void* const* d_in, const int* in_sizes, int n_in,
                              void* d_out, int out_size, void* d_ws, size_t ws_size,
                              hipStream_t stream) {
  const float* supp   = (const float*)d_in[0];
  const float* qry    = (const float*)d_in[1];
  const int*   labels = (const int*)d_in[2];
  const float* Wqk    = (const float*)d_in[3];
  const float* Wv     = (const float*)d_in[4];
  float* out = (float*)d_out;

  // ws layout (~4.6 MB)
  uint16_t* Whi = (uint16_t*)d_ws;                  // [2][128][512]
  uint16_t* Qt  = Whi + (size_t)2 * ND * NC;        // [32][196][128]
  uint16_t* Kt  = Qt  + (size_t)NB * NP * ND;       // [25][208][128]
  uint16_t* Vt  = Kt  + (size_t)NSUP * JS * ND;     // [25][128][208]
  float* outVq = out + (size_t)NB * KCLS * ND * NP; // query_v_flat region

  wconv_kernel<<<64, 256, 0, stream>>>(Wqk, Wv, Whi);
  gemm_kernel<<<741, 256, 0, stream>>>(supp, qry, Whi, Qt, Kt, Vt, outVq);
  attn_kernel<<<520, 256, 0, stream>>>(Qt, Kt, Vt, labels, out);
}